// Round 8
// baseline (387.374 us; speedup 1.0000x reference)
//
#include <hip/hip_runtime.h>
#include <hip/hip_fp16.h>

typedef _Float16 f16x8 __attribute__((ext_vector_type(8)));
typedef float    f32x4 __attribute__((ext_vector_type(4)));

#define TILE_W 16
#define TILE_H 8
#define HALO_W 22      // TILE_W + 6
#define HALO_H 14      // TILE_H + 6
#define KK     7
#define NCLASS 49
#define IMW    256
#define IMH    256
#define HW     65536   // 256*256
#define HH     308     // HALO_H * HALO_W
#define NV     42      // V-rows 0..41 (n00 <= 40)
#define WROW   34      // W row stride in DWORDS (8B-aligned)

// LDS layout (dwords), total 6608 -> 26432 B -> 6 blocks/CU (12 waves/CU,
// 6 INDEPENDENT phase streams vs 3 before):
#define OFF_OMV    0       // [42][128] packed half2 (V[v].lo, V[v].hi) = 5376
#define OFF_HALO2  5376    // uint2[308] {pf, n8} (n8=n00*8, ~0u = OOB) =  616
#define SH_TOTAL   6608
// overlays (lifetime-disjoint):
//   iml4 float4[308] @5376 (1232 dw, ends 6608)   (halo2 dead after P3)
//   W    uint[128*34] @0   (4352 dw)              (omV dead after P4 reads)
#define OFF_IML4   5376

// workspace layout (dwords):
//   WS_B   @0    : B-frag table [3][4][64] uint4               = 3072 dw
//   WS_KVP @3072 : uint2 KVP[49][42]
//                  .x=(K[n,s],K[n+7,s]) .y=(K[n+1,s],K[n+8,s]) = 4116 dw
#define WS_B    0
#define WS_KVP  3072

__device__ __forceinline__ unsigned h2u(__half2 h) { union { __half2 h; unsigned u; } c; c.h = h; return c.u; }
__device__ __forceinline__ __half2  u2h(unsigned u) { union { __half2 h; unsigned u; } c; c.u = u; return c.h; }

// ---------------- setup: precompute f16 tables once per dispatch ---------------
__global__ void gtnet_setup(const float* __restrict__ m_kernel, unsigned* __restrict__ ws)
{
    const int tid = threadIdx.x;
    // B-fragment table: idx = (kit*4+nt)*64 + lane; uint4 = 4 K-dwords j=0..3
    for (int idx = tid; idx < 768; idx += 256) {
        int lane = idx & 63, kitnt = idx >> 6;
        int kit = kitnt >> 2, nt = kitnt & 3;
        int vb0 = (lane >> 4) * 4, tcol = lane & 15;
        int t = nt * 16 + tcol; int tc = (t > 48) ? 48 : t;
        uint4 o;
        unsigned* op = (unsigned*)&o;
        #pragma unroll
        for (int j = 0; j < 4; j++) {
            int v = kit * 16 + vb0 + j;
            float lo = (v <= 41) ? m_kernel[v * NCLASS + tc]        : 0.0f;
            float hi = (v <= 41) ? m_kernel[(v + KK) * NCLASS + tc] : 0.0f;
            op[j] = h2u(__halves2half2(__float2half_rn(lo), __float2half_rn(hi)));
        }
        ((uint4*)ws)[idx] = o;
    }
    // KVP paired table: one 8B-aligned uint2 per (s, n00) -> single dwordx2 load
    uint2* kvp = (uint2*)(ws + WS_KVP);
    for (int i = tid; i < NCLASS * NV; i += 256) {
        int s = i / NV, n = i - (i / NV) * NV;
        float k0 = m_kernel[n * NCLASS + s];
        float k7 = m_kernel[(n + 7) * NCLASS + s];              // n<=41 -> n+7<=48
        float k1 = m_kernel[(n + 1) * NCLASS + s];              // n+1<=42<=48
        float k8 = (n + 8 <= 48) ? m_kernel[(n + 8) * NCLASS + s] : 0.0f;
        uint2 o;
        o.x = h2u(__halves2half2(__float2half_rn(k0), __float2half_rn(k7)));
        o.y = h2u(__halves2half2(__float2half_rn(k1), __float2half_rn(k8)));
        kvp[i] = o;
    }
}

__global__ __launch_bounds__(128, 3)
void gtnet_kernel(const float* __restrict__ im_input,
                  const float* __restrict__ gt_motion,
                  float* __restrict__ out_pred,
                  float* __restrict__ out_mask,
                  const unsigned* __restrict__ ws)
{
    __shared__ __align__(16) unsigned SH[SH_TOTAL];
    unsigned* const omV   = SH + OFF_OMV;
    uint2*    const halo2 = (uint2*)(SH + OFF_HALO2);   // {pf, n8}
    float4*   const iml4  = (float4*)(SH + OFF_IML4);

    const int tid  = threadIdx.x;                       // 0..127
    const int lane = tid & 63, wv_id = tid >> 6;        // 2 waves
    const int tx = tid & 15, ty = tid >> 4;             // ty 0..7
    const int x0 = blockIdx.x * TILE_W, y0 = blockIdx.y * TILE_H;
    const int b  = blockIdx.z;
    const int x = x0 + tx, y = y0 + ty;

    const float* mot_x = gt_motion + (size_t)b * 2 * HW;  // channel 0 -> ax
    const float* mot_y = mot_x + HW;                      // channel 1 -> ay
    const float* imP   = im_input + ((size_t)b * 6 + 3) * HW;  // last 3 channels

    // ---------------- phase 0: im halo -> REGISTERS (LDS write deferred) -------
    float4 imr[3];
    #pragma unroll
    for (int k = 0; k < 3; k++) {
        int i = tid + k * 128;
        float4 v = make_float4(0.0f, 0.0f, 0.0f, 0.0f);
        if (i < HH) {
            int hy = i / HALO_W, hx = i - hy * HALO_W;
            int gy = y0 - 3 + hy, gx = x0 - 3 + hx;
            if (gy >= 0 && gy < IMH && gx >= 0 && gx < IMW) {
                int off = gy * IMW + gx;
                v.x = imP[off];
                v.y = imP[off + HW];
                v.z = imP[off + 2 * HW];
            }
        }
        imr[k] = v;
    }

    // ---------------- phase 1: staging ----------------
    #pragma unroll
    for (int k = 0; k < 3; k++) {                       // packed motion halo
        int i = tid + k * 128;
        if (i < HH) {
            int hy = i / HALO_W, hx = i - hy * HALO_W;
            int gy = y0 - 3 + hy, gx = x0 - 3 + hx;
            unsigned pf = 0u, n8b = 0xFFFFFFFFu;        // ~0 = OOB sentinel
            if (gy >= 0 && gy < IMH && gx >= 0 && gx < IMW) {
                int off = gy * IMW + gx;
                float ay = mot_y[off] + 3.0f;
                float ax = mot_x[off] + 3.0f;
                float iyf = floorf(ay), ixf = floorf(ax);
                float fy = ay - iyf,    fx = ax - ixf;
                int n00 = (int)iyf * KK + (int)ixf;
                n00 = (n00 < 0) ? 0 : ((n00 > 40) ? 40 : n00);
                pf  = h2u(__halves2half2(__float2half_rn(fy), __float2half_rn(fx)));
                n8b = (unsigned)(n00 * 8);
            }
            uint2 hv; hv.x = pf; hv.y = n8b;
            halo2[i] = hv;                              // ds_write_b64
        }
    }
    {   // zero omV (5376 dwords) via b128
        uint4* p = reinterpret_cast<uint4*>(omV);
        for (int i = tid; i < (NV * 128) / 4; i += 128) p[i] = make_uint4(0, 0, 0, 0);
    }

    __syncthreads();

    // ---------------- phase 2: m_mask dense write (exact f32) ----------------
    {
        int off = y * IMW + x;
        float ay = mot_y[off] + 3.0f;
        float ax = mot_x[off] + 3.0f;
        float iyf = floorf(ay), ixf = floorf(ax);
        float fy = ay - iyf,    fx = ax - ixf;
        int   iy = (int)iyf,    ix = (int)ixf;
        float wyA[KK], wxB[KK];
        #pragma unroll
        for (int a = 0; a < KK; a++) {
            wyA[a] = (a == iy) ? (1.0f - fy) : ((a == iy + 1) ? fy : 0.0f);
            wxB[a] = (a == ix) ? (1.0f - fx) : ((a == ix + 1) ? fx : 0.0f);
        }
        float* mm = out_mask + (size_t)b * NCLASS * HW + off;
        #pragma unroll
        for (int a = 0; a < KK; a++)
            #pragma unroll
            for (int bb = 0; bb < KK; bb++)
                mm[(size_t)(a * KK + bb) * HW] = wyA[a] * wxB[bb];
    }

    // ---------------- phase 3: scatter — b64 halo + VMEM KVP + om RMW ----------
    // thread-private om column (px = tid): no cross-thread collisions; per-thread
    // RMW ordering guaranteed by in-order DS issue. KV pairs from global KVP
    // (L1/L2-hot) -> off the DS pipe.
    unsigned* const omCol = omV + tid;
    const uint2* const kvpT = (const uint2*)(ws + WS_KVP);
    const unsigned c_m11 = 0x3C00BC00u;   // (lo=-1.0h, hi=+1.0h)
    const unsigned c_10  = 0x00003C00u;   // (lo=+1.0h, hi= 0.0h)
    #pragma unroll
    for (int u = 0; u < KK; u++) {
        uint2 hvr[KK];
        #pragma unroll
        for (int v = 0; v < KK; v++)                    // batch: 7 x ds_read_b64
            hvr[v] = halo2[(ty + u) * HALO_W + (tx + v)];
        unsigned n8r[KK]; uint2 kvr[KK];
        #pragma unroll
        for (int v = 0; v < KK; v++) {                  // batch: 7 x dwordx2 (L1)
            const int s = u * KK + v;                   // compile-time
            unsigned n8u = hvr[v].y;
            n8r[v] = (n8u == 0xFFFFFFFFu) ? 0u : n8u;
            kvr[v] = *(const uint2*)((const char*)(kvpT + s * NV) + n8r[v]);
        }
        #pragma unroll
        for (int v = 0; v < KK; v++) {
            unsigned pf = hvr[v].x;
            unsigned wyb, wx2;
            // wy = (1-fy, fy) : one pk_fma, fy broadcast via op_sel
            asm("v_pk_fma_f16 %0, %1, %2, %3 op_sel:[0,0,0] op_sel_hi:[0,1,1]"
                : "=v"(wyb) : "v"(pf), "v"(c_m11), "v"(c_10));
            // wx2 = (1-fx, fx) : fx broadcast via op_sel
            asm("v_pk_fma_f16 %0, %1, %2, %3 op_sel:[1,0,0] op_sel_hi:[1,1,1]"
                : "=v"(wx2) : "v"(pf), "v"(c_m11), "v"(c_10));
            wyb = (hvr[v].y == 0xFFFFFFFFu) ? 0u : wyb; // OOB -> zero weights
            unsigned tA, tB;
            // tA = wy * bcast_lo(wx2) = (w00, w10); tB = wy * bcast_hi = (w01, w11)
            asm("v_pk_mul_f16 %0, %1, %2 op_sel:[0,0] op_sel_hi:[1,0]"
                : "=v"(tA) : "v"(wyb), "v"(wx2));
            asm("v_pk_mul_f16 %0, %1, %2 op_sel:[0,1] op_sel_hi:[1,1]"
                : "=v"(tB) : "v"(wyb), "v"(wx2));
            unsigned* ob = (unsigned*)((char*)omCol + n8r[v] * 64);  // n00*512 B
            unsigned o0 = ob[0], o1 = ob[128];          // ds_read2_b32 (0,128)
            __half2 cA = __hmul2(u2h(tA), u2h(kvr[v].x));
            __half2 cB = __hmul2(u2h(tB), u2h(kvr[v].y));
            ob[0]   = h2u(__hadd2(u2h(o0), cA));        // ds_write2_b32 (0,128)
            ob[128] = h2u(__hadd2(u2h(o1), cB));
        }
    }

    __syncthreads();   // omV complete; halo2 now dead

    // ---------------- phase 4 prologue: B fragments via 12 x b128 from ws ------
    uint4 braw[3][4];
    {
        const uint4* bsrc = (const uint4*)(ws + WS_B);
        #pragma unroll
        for (int kit = 0; kit < 3; kit++)
            #pragma unroll
            for (int nt = 0; nt < 4; nt++)
                braw[kit][nt] = bsrc[(kit * 4 + nt) * 64 + lane];
    }

    // ---------------- phase 3.5: im registers -> LDS (overlay dead region) -----
    #pragma unroll
    for (int k = 0; k < 3; k++) {
        int i = tid + k * 128;
        if (i < HH) iml4[i] = imr[k];                   // ds_write_b128
    }

    // ---------------- phase 4+5: K=96 MFMA GEMM, A = V dwords DIRECT -----------
    // W[px][t] = sum_v loV[v]*K[v][t] + hiV[v]*K[v+7][t]
    f32x4 acc[4][4];
    #pragma unroll
    for (int mt = 0; mt < 4; mt++)
        #pragma unroll
        for (int nt = 0; nt < 4; nt++)
            acc[mt][nt] = (f32x4){0.0f, 0.0f, 0.0f, 0.0f};

    const int vb0  = (lane >> 4) * 4;
    const int tcol = lane & 15;
    #pragma unroll
    for (int kit = 0; kit < 3; kit++) {
        f16x8 afk[4];
        #pragma unroll
        for (int mt = 0; mt < 4; mt++) {
            int px = wv_id * 64 + mt * 16 + tcol;       // 0..127
            const unsigned* pxb = omV + px;
            int vb = kit * 16 + vb0;
            union { unsigned u[4]; f16x8 v; } au;
            #pragma unroll
            for (int j = 0; j < 4; j++) {
                unsigned d = pxb[(vb + j) * 128];        // ds_read2-mergeable
                au.u[j] = (vb + j <= 41) ? d : 0u;       // mask garbage rows
            }
            afk[mt] = au.v;
        }
        #pragma unroll
        for (int mt = 0; mt < 4; mt++) {
            #pragma unroll
            for (int nt = 0; nt < 4; nt++) {
                union { uint4 q; f16x8 v; } bc; bc.q = braw[kit][nt];
                acc[mt][nt] = __builtin_amdgcn_mfma_f32_16x16x32_f16(afk[mt], bc.v, acc[mt][nt], 0, 0, 0);
            }
        }
    }

    __syncthreads();   // all omV reads done before W overwrites the region

    // ---------------- phase 5b: packed W write (16 x ds_write2_b32) ------------
    // C/D layout: col=lane&15 (t0), row=(lane>>4)*4+reg (px)
    // dword t0 of row px = (t0, t0+16); dword 16+t0 = (t0+32, t0+48)
    #pragma unroll
    for (int mt = 0; mt < 4; mt++) {
        #pragma unroll
        for (int r = 0; r < 4; r++) {
            int px = wv_id * 64 + mt * 16 + (lane >> 4) * 4 + r;
            unsigned* wrow = SH + px * WROW + tcol;
            unsigned v0 = h2u(__halves2half2(__float2half_rn(acc[mt][0][r]),
                                             __float2half_rn(acc[mt][1][r])));
            unsigned v1 = h2u(__halves2half2(__float2half_rn(acc[mt][2][r]),
                                             __float2half_rn(acc[mt][3][r])));
            wrow[0]  = v0;                               // ds_write2_b32 (0,16)
            wrow[16] = v1;
        }
    }

    __syncthreads();   // W complete; iml writes also ordered before here

    // ---------------- phase 6: apply effective 7x7 kernel ----------------------
    union { uint2 q[16]; unsigned d[32]; } wr;           // 16 x b64 (read2-merged)
    const uint2* wp = (const uint2*)(SH + tid * WROW);   // 136B stride, 8B aligned
    #pragma unroll
    for (int c = 0; c < 16; c++) wr.q[c] = wp[c];

    // static half extraction per t
    #define WHALF(t) ( (t) < 16 ? __low2half(u2h(wr.d[(t)])) :           \
                       (t) < 32 ? __high2half(u2h(wr.d[(t) - 16])) :     \
                       (t) < 48 ? __low2half(u2h(wr.d[(t) - 16])) :      \
                                  __high2half(u2h(wr.d[16])) )

    float a0 = 0.0f, a1 = 0.0f, a2 = 0.0f;
    #pragma unroll
    for (int p = 0; p < KK; p++) {
        #pragma unroll
        for (int qq = 0; qq < KK; qq++) {
            float wvv = __half2float(WHALF(p * KK + qq));
            int   hq  = (ty + p) * HALO_W + (tx + qq);
            float4 iv = iml4[hq];                        // 1x ds_read_b128
            a0 = fmaf(wvv, iv.x, a0);
            a1 = fmaf(wvv, iv.y, a1);
            a2 = fmaf(wvv, iv.z, a2);
        }
    }
    #undef WHALF
    float* pr = out_pred + (size_t)b * 3 * HW + y * IMW + x;
    pr[0]      = a0;
    pr[HW]     = a1;
    pr[2 * HW] = a2;
}

extern "C" void kernel_launch(void* const* d_in, const int* in_sizes, int n_in,
                              void* d_out, int out_size, void* d_ws, size_t ws_size,
                              hipStream_t stream) {
    const float* im_input  = (const float*)d_in[0];
    // d_in[1] = im_output: unused by the reference computation
    const float* gt_motion = (const float*)d_in[2];
    const float* m_kernel  = (const float*)d_in[3];

    float* pred = (float*)d_out;                        // (16,3,256,256)
    float* mask = pred + (size_t)16 * 3 * HW;           // (16,49,256,256)

    hipLaunchKernelGGL(gtnet_setup, dim3(1), dim3(256), 0, stream,
                       m_kernel, (unsigned*)d_ws);

    dim3 grid(IMW / TILE_W, IMH / TILE_H, 16);
    dim3 block(128);
    hipLaunchKernelGGL(gtnet_kernel, grid, block, 0, stream,
                       im_input, gt_motion, pred, mask, (const unsigned*)d_ws);
}

// Round 9
// 355.492 us; speedup vs baseline: 1.0897x; 1.0897x over previous
//
#include <hip/hip_runtime.h>
#include <hip/hip_fp16.h>

typedef _Float16 f16x8 __attribute__((ext_vector_type(8)));
typedef float    f32x4 __attribute__((ext_vector_type(4)));

#define TILE_W 32
#define TILE_H 8
#define HALO_W 38      // TILE_W + 6
#define HALO_H 14      // TILE_H + 6
#define KK     7
#define NCLASS 49
#define IMW    256
#define IMH    256
#define HW     65536   // 256*256
#define HH     532     // HALO_H * HALO_W
#define NV     42      // V-rows 0..41 (n00 <= 40)
#define WROW   34      // W row stride in DWORDS (8B-aligned)

// LDS layout (dwords), total 12880 -> 51520 B -> 3 blocks/CU:
#define OFF_OMV    0       // [2][42][128] packed half2 (V[v], V[v+7])   = 10752
#define OFF_HALO2  10752   // uint2[532] {pf, n8} (n8=n00*8, ~0u = OOB)  =  1064
#define SH_TOTAL   12880
// overlays (lifetime-disjoint):
//   iml4 float4[532] @10752 (2128 dw, ends 12880)  (halo2 dead after P3)
//   W    uint[256*34] @0    (8704 dw)              (omV dead after P4 reads)
#define OFF_IML4   10752

// workspace layout (dwords):
//   WS_B   @0    : B-frag table [3][4][64] uint4               = 3072 dw
//   WS_KVP @3072 : uint2 KVP[49][42]
//                  .x=(K[n,s],K[n+7,s]) .y=(K[n+1,s],K[n+8,s]) = 4116 dw
#define WS_B    0
#define WS_KVP  3072

__device__ __forceinline__ unsigned h2u(__half2 h) { union { __half2 h; unsigned u; } c; c.h = h; return c.u; }
__device__ __forceinline__ __half2  u2h(unsigned u) { union { __half2 h; unsigned u; } c; c.u = u; return c.h; }

// ---------------- setup: precompute f16 tables once per dispatch ---------------
__global__ void gtnet_setup(const float* __restrict__ m_kernel, unsigned* __restrict__ ws)
{
    const int tid = threadIdx.x;
    // B-fragment table: idx = (kit*4+nt)*64 + lane; uint4 = 4 K-dwords j=0..3
    for (int idx = tid; idx < 768; idx += 256) {
        int lane = idx & 63, kitnt = idx >> 6;
        int kit = kitnt >> 2, nt = kitnt & 3;
        int vb0 = (lane >> 4) * 4, tcol = lane & 15;
        int t = nt * 16 + tcol; int tc = (t > 48) ? 48 : t;
        uint4 o;
        unsigned* op = (unsigned*)&o;
        #pragma unroll
        for (int j = 0; j < 4; j++) {
            int v = kit * 16 + vb0 + j;
            float lo = (v <= 41) ? m_kernel[v * NCLASS + tc]        : 0.0f;
            float hi = (v <= 41) ? m_kernel[(v + KK) * NCLASS + tc] : 0.0f;
            op[j] = h2u(__halves2half2(__float2half_rn(lo), __float2half_rn(hi)));
        }
        ((uint4*)ws)[idx] = o;
    }
    // KVP paired table: one 8B-aligned uint2 per (s, n00) -> single dwordx2 load
    uint2* kvp = (uint2*)(ws + WS_KVP);
    for (int i = tid; i < NCLASS * NV; i += 256) {
        int s = i / NV, n = i - (i / NV) * NV;
        float k0 = m_kernel[n * NCLASS + s];
        float k7 = m_kernel[(n + 7) * NCLASS + s];              // n<=41 -> n+7<=48
        float k1 = m_kernel[(n + 1) * NCLASS + s];              // n+1<=42<=48
        float k8 = (n + 8 <= 48) ? m_kernel[(n + 8) * NCLASS + s] : 0.0f;
        uint2 o;
        o.x = h2u(__halves2half2(__float2half_rn(k0), __float2half_rn(k7)));
        o.y = h2u(__halves2half2(__float2half_rn(k1), __float2half_rn(k8)));
        kvp[i] = o;
    }
}

__global__ __launch_bounds__(256, 3)
void gtnet_kernel(const float* __restrict__ im_input,
                  const float* __restrict__ gt_motion,
                  float* __restrict__ out_pred,
                  float* __restrict__ out_mask,
                  const unsigned* __restrict__ ws)
{
    __shared__ __align__(16) unsigned SH[SH_TOTAL];
    unsigned* const omV   = SH + OFF_OMV;
    uint2*    const halo2 = (uint2*)(SH + OFF_HALO2);   // {pf, n8}
    float4*   const iml4  = (float4*)(SH + OFF_IML4);

    const int tid  = threadIdx.x;                       // 0..255
    const int lane = tid & 63, wv_id = tid >> 6;
    const int tx = tid & 31, ty = tid >> 5;             // 32x8 pixel map
    const int x0 = blockIdx.x * TILE_W, y0 = blockIdx.y * TILE_H;
    const int b  = blockIdx.z;
    const int x = x0 + tx, y = y0 + ty;

    const float* mot_x = gt_motion + (size_t)b * 2 * HW;  // channel 0 -> ax
    const float* mot_y = mot_x + HW;                      // channel 1 -> ay
    const float* imP   = im_input + ((size_t)b * 6 + 3) * HW;  // last 3 channels

    // ---------------- phase 0: im halo -> REGISTERS (LDS write deferred) -------
    float4 imr[3];
    #pragma unroll
    for (int k = 0; k < 3; k++) {
        int i = tid + k * 256;
        float4 v = make_float4(0.0f, 0.0f, 0.0f, 0.0f);
        if (i < HH) {
            int hy = i / HALO_W, hx = i - hy * HALO_W;
            int gy = y0 - 3 + hy, gx = x0 - 3 + hx;
            if (gy >= 0 && gy < IMH && gx >= 0 && gx < IMW) {
                int off = gy * IMW + gx;
                v.x = imP[off];
                v.y = imP[off + HW];
                v.z = imP[off + 2 * HW];
            }
        }
        imr[k] = v;
    }

    // ---------------- phase 1: staging ----------------
    #pragma unroll
    for (int k = 0; k < 3; k++) {                       // packed motion halo
        int i = tid + k * 256;
        if (i < HH) {
            int hy = i / HALO_W, hx = i - hy * HALO_W;
            int gy = y0 - 3 + hy, gx = x0 - 3 + hx;
            unsigned pf = 0u, n8b = 0xFFFFFFFFu;        // ~0 = OOB sentinel
            if (gy >= 0 && gy < IMH && gx >= 0 && gx < IMW) {
                int off = gy * IMW + gx;
                float ay = mot_y[off] + 3.0f;
                float ax = mot_x[off] + 3.0f;
                float iyf = floorf(ay), ixf = floorf(ax);
                float fy = ay - iyf,    fx = ax - ixf;
                int n00 = (int)iyf * KK + (int)ixf;
                n00 = (n00 < 0) ? 0 : ((n00 > 40) ? 40 : n00);
                pf  = h2u(__halves2half2(__float2half_rn(fy), __float2half_rn(fx)));
                n8b = (unsigned)(n00 * 8);
            }
            uint2 hv; hv.x = pf; hv.y = n8b;
            halo2[i] = hv;                              // ds_write_b64
        }
    }
    {   // zero omV (10752 dwords) via b128
        uint4* p = reinterpret_cast<uint4*>(omV);
        for (int i = tid; i < (2 * NV * 128) / 4; i += 256) p[i] = make_uint4(0, 0, 0, 0);
    }

    __syncthreads();

    // ---------------- phase 2: m_mask dense write (exact f32, FULL 128B lines) -
    // 32-wide tile: each wave's stores per class = 2 rows x 32 px = 2 full
    // 128B-aligned cache lines, entirely block-private -> no partial-line
    // write amplification, half the L2 store requests of the 16-wide tile.
    {
        int off = y * IMW + x;
        float ay = mot_y[off] + 3.0f;
        float ax = mot_x[off] + 3.0f;
        float iyf = floorf(ay), ixf = floorf(ax);
        float fy = ay - iyf,    fx = ax - ixf;
        int   iy = (int)iyf,    ix = (int)ixf;
        float wyA[KK], wxB[KK];
        #pragma unroll
        for (int a = 0; a < KK; a++) {
            wyA[a] = (a == iy) ? (1.0f - fy) : ((a == iy + 1) ? fy : 0.0f);
            wxB[a] = (a == ix) ? (1.0f - fx) : ((a == ix + 1) ? fx : 0.0f);
        }
        float* mm = out_mask + (size_t)b * NCLASS * HW + off;
        #pragma unroll
        for (int a = 0; a < KK; a++)
            #pragma unroll
            for (int bb = 0; bb < KK; bb++)
                mm[(size_t)(a * KK + bb) * HW] = wyA[a] * wxB[bb];
    }

    // ---------------- phase 3: scatter — b64 halo + VMEM KVP + om RMW ----------
    // thread-private om column (px = tid&127, half = tid>>7): no cross-thread
    // collisions; per-thread RMW ordering guaranteed by in-order DS issue.
    // KV pairs from global KVP (L1/L2-hot) -> off the DS pipe.
    unsigned* const omHalf = omV + (tid >> 7) * (NV * 128) + (tid & 127);
    const uint2* const kvpT = (const uint2*)(ws + WS_KVP);
    const unsigned c_m11 = 0x3C00BC00u;   // (lo=-1.0h, hi=+1.0h)
    const unsigned c_10  = 0x00003C00u;   // (lo=+1.0h, hi= 0.0h)
    #pragma unroll
    for (int u = 0; u < KK; u++) {
        uint2 hvr[KK];
        #pragma unroll
        for (int v = 0; v < KK; v++)                    // batch: 7 x ds_read_b64
            hvr[v] = halo2[(ty + u) * HALO_W + (tx + v)];
        unsigned n8r[KK]; uint2 kvr[KK];
        #pragma unroll
        for (int v = 0; v < KK; v++) {                  // batch: 7 x dwordx2 (L1)
            const int s = u * KK + v;                   // compile-time
            unsigned n8u = hvr[v].y;
            n8r[v] = (n8u == 0xFFFFFFFFu) ? 0u : n8u;
            kvr[v] = *(const uint2*)((const char*)(kvpT + s * NV) + n8r[v]);
        }
        #pragma unroll
        for (int v = 0; v < KK; v++) {
            unsigned pf = hvr[v].x;
            unsigned wyb, wx2;
            // wy = (1-fy, fy) : one pk_fma, fy broadcast via op_sel
            asm("v_pk_fma_f16 %0, %1, %2, %3 op_sel:[0,0,0] op_sel_hi:[0,1,1]"
                : "=v"(wyb) : "v"(pf), "v"(c_m11), "v"(c_10));
            // wx2 = (1-fx, fx) : fx broadcast via op_sel
            asm("v_pk_fma_f16 %0, %1, %2, %3 op_sel:[1,0,0] op_sel_hi:[1,1,1]"
                : "=v"(wx2) : "v"(pf), "v"(c_m11), "v"(c_10));
            wyb = (hvr[v].y == 0xFFFFFFFFu) ? 0u : wyb; // OOB -> zero weights
            unsigned tA, tB;
            // tA = wy * bcast_lo(wx2) = (w00, w10); tB = wy * bcast_hi = (w01, w11)
            asm("v_pk_mul_f16 %0, %1, %2 op_sel:[0,0] op_sel_hi:[1,0]"
                : "=v"(tA) : "v"(wyb), "v"(wx2));
            asm("v_pk_mul_f16 %0, %1, %2 op_sel:[0,1] op_sel_hi:[1,1]"
                : "=v"(tB) : "v"(wyb), "v"(wx2));
            unsigned* ob = (unsigned*)((char*)omHalf + n8r[v] * 64);  // n00*512 B
            unsigned o0 = ob[0], o1 = ob[128];          // ds_read2_b32 (0,128)
            __half2 cA = __hmul2(u2h(tA), u2h(kvr[v].x));
            __half2 cB = __hmul2(u2h(tB), u2h(kvr[v].y));
            ob[0]   = h2u(__hadd2(u2h(o0), cA));        // ds_write2_b32 (0,128)
            ob[128] = h2u(__hadd2(u2h(o1), cB));
        }
    }

    __syncthreads();   // omV complete; halo2 now dead

    // ---------------- phase 4 prologue: B fragments via 12 x b128 from ws ------
    uint4 braw[3][4];
    {
        const uint4* bsrc = (const uint4*)(ws + WS_B);
        #pragma unroll
        for (int kit = 0; kit < 3; kit++)
            #pragma unroll
            for (int nt = 0; nt < 4; nt++)
                braw[kit][nt] = bsrc[(kit * 4 + nt) * 64 + lane];
    }

    // ---------------- phase 3.5: im registers -> LDS (overlay dead region) -----
    #pragma unroll
    for (int k = 0; k < 3; k++) {
        int i = tid + k * 256;
        if (i < HH) iml4[i] = imr[k];                   // ds_write_b128
    }

    // ---------------- phase 4+5: K=96 MFMA GEMM, A = V dwords DIRECT -----------
    // W[px][t] = sum_v loV[v]*K[v][t] + hiV[v]*K[v+7][t]
    f32x4 acc[4][4];
    #pragma unroll
    for (int mt = 0; mt < 4; mt++)
        #pragma unroll
        for (int nt = 0; nt < 4; nt++)
            acc[mt][nt] = (f32x4){0.0f, 0.0f, 0.0f, 0.0f};

    const int vb0  = (lane >> 4) * 4;
    const int tcol = lane & 15;
    #pragma unroll
    for (int kit = 0; kit < 3; kit++) {
        f16x8 afk[4];
        #pragma unroll
        for (int mt = 0; mt < 4; mt++) {
            int px = wv_id * 64 + mt * 16 + tcol;
            const unsigned* pxb = omV + (px >> 7) * (NV * 128) + (px & 127);
            int vb = kit * 16 + vb0;
            union { unsigned u[4]; f16x8 v; } au;
            #pragma unroll
            for (int j = 0; j < 4; j++) {
                unsigned d = pxb[(vb + j) * 128];        // ds_read2-mergeable
                au.u[j] = (vb + j <= 41) ? d : 0u;       // mask garbage rows
            }
            afk[mt] = au.v;
        }
        #pragma unroll
        for (int mt = 0; mt < 4; mt++) {
            #pragma unroll
            for (int nt = 0; nt < 4; nt++) {
                union { uint4 q; f16x8 v; } bc; bc.q = braw[kit][nt];
                acc[mt][nt] = __builtin_amdgcn_mfma_f32_16x16x32_f16(afk[mt], bc.v, acc[mt][nt], 0, 0, 0);
            }
        }
    }

    __syncthreads();   // all omV reads done before W overwrites the region

    // ---------------- phase 5b: packed W write (16 x ds_write2_b32) ------------
    // C/D layout: col=lane&15 (t0), row=(lane>>4)*4+reg (px)
    // dword t0 of row px = (t0, t0+16); dword 16+t0 = (t0+32, t0+48)
    #pragma unroll
    for (int mt = 0; mt < 4; mt++) {
        #pragma unroll
        for (int r = 0; r < 4; r++) {
            int px = wv_id * 64 + mt * 16 + (lane >> 4) * 4 + r;
            unsigned* wrow = SH + px * WROW + tcol;
            unsigned v0 = h2u(__halves2half2(__float2half_rn(acc[mt][0][r]),
                                             __float2half_rn(acc[mt][1][r])));
            unsigned v1 = h2u(__halves2half2(__float2half_rn(acc[mt][2][r]),
                                             __float2half_rn(acc[mt][3][r])));
            wrow[0]  = v0;                               // ds_write2_b32 (0,16)
            wrow[16] = v1;
        }
    }

    __syncthreads();   // W complete; iml writes also ordered before here

    // ---------------- phase 6: apply effective 7x7 kernel ----------------------
    union { uint2 q[16]; unsigned d[32]; } wr;           // 16 x b64 (read2-merged)
    const uint2* wp = (const uint2*)(SH + tid * WROW);   // 136B stride, 8B aligned
    #pragma unroll
    for (int c = 0; c < 16; c++) wr.q[c] = wp[c];

    // static half extraction per t
    #define WHALF(t) ( (t) < 16 ? __low2half(u2h(wr.d[(t)])) :           \
                       (t) < 32 ? __high2half(u2h(wr.d[(t) - 16])) :     \
                       (t) < 48 ? __low2half(u2h(wr.d[(t) - 16])) :      \
                                  __high2half(u2h(wr.d[16])) )

    float a0 = 0.0f, a1 = 0.0f, a2 = 0.0f;
    #pragma unroll
    for (int p = 0; p < KK; p++) {
        #pragma unroll
        for (int qq = 0; qq < KK; qq++) {
            float wvv = __half2float(WHALF(p * KK + qq));
            int   hq  = (ty + p) * HALO_W + (tx + qq);
            float4 iv = iml4[hq];                        // 1x ds_read_b128
            a0 = fmaf(wvv, iv.x, a0);
            a1 = fmaf(wvv, iv.y, a1);
            a2 = fmaf(wvv, iv.z, a2);
        }
    }
    #undef WHALF
    float* pr = out_pred + (size_t)b * 3 * HW + y * IMW + x;
    pr[0]      = a0;      // full 128B lines: 32 px x 4B, 128B-aligned
    pr[HW]     = a1;
    pr[2 * HW] = a2;
}

extern "C" void kernel_launch(void* const* d_in, const int* in_sizes, int n_in,
                              void* d_out, int out_size, void* d_ws, size_t ws_size,
                              hipStream_t stream) {
    const float* im_input  = (const float*)d_in[0];
    // d_in[1] = im_output: unused by the reference computation
    const float* gt_motion = (const float*)d_in[2];
    const float* m_kernel  = (const float*)d_in[3];

    float* pred = (float*)d_out;                        // (16,3,256,256)
    float* mask = pred + (size_t)16 * 3 * HW;           // (16,49,256,256)

    hipLaunchKernelGGL(gtnet_setup, dim3(1), dim3(256), 0, stream,
                       m_kernel, (unsigned*)d_ws);

    dim3 grid(IMW / TILE_W, IMH / TILE_H, 16);
    dim3 block(256);
    hipLaunchKernelGGL(gtnet_kernel, grid, block, 0, stream,
                       im_input, gt_motion, pred, mask, (const unsigned*)d_ws);
}

// Round 10
// 319.869 us; speedup vs baseline: 1.2110x; 1.1114x over previous
//
#include <hip/hip_runtime.h>
#include <hip/hip_fp16.h>

typedef _Float16 f16x8 __attribute__((ext_vector_type(8)));
typedef float    f32x4 __attribute__((ext_vector_type(4)));

#define TILE   16
#define HALO   22      // TILE + 6
#define KK     7
#define NCLASS 49
#define IMW    256
#define IMH    256
#define HW     65536   // 256*256
#define HH     484     // HALO*HALO
#define NV     42      // V-rows 0..41 (n00 <= 40)
#define WROW   34      // W row stride in DWORDS (8B-aligned)

// LDS layout (dwords), total 12204 -> 48816 B -> 3 blocks/CU:
#define OFF_OMV    0        // [2][42][128] packed half2 (V[v].lo, V[v].hi) = 10752
#define OFF_HALO2  10752    // uint2[484] {pf, n8}  (n8 = n00*8, ~0u = OOB) =  968
#define SH_TOTAL   12204
// overlays (lifetime-disjoint):
//   iml64 float2[484] @10752, iml32 float[484] @11720  (halo2 dead after P3)
//   W     uint[256*34] @0    (8704 dw)                 (omV dead after P4 reads)
#define OFF_IML64  10752
#define OFF_IML32  11720

// workspace layout (dwords):
//   WS_B   @0    : B-frag table [3][4][64] uint4            = 3072 dw
//   WS_KVP @3072 : uint2 KVP[49][42]
//                  .x=(K[n,s],K[n+7,s]) .y=(K[n+1,s],K[n+8,s]) = 4116 dw
#define WS_B    0
#define WS_KVP  3072

__device__ __forceinline__ unsigned h2u(__half2 h) { union { __half2 h; unsigned u; } c; c.h = h; return c.u; }
__device__ __forceinline__ __half2  u2h(unsigned u) { union { __half2 h; unsigned u; } c; c.u = u; return c.h; }

// ---------------- setup: precompute f16 tables once per dispatch ---------------
__global__ void gtnet_setup(const float* __restrict__ m_kernel, unsigned* __restrict__ ws)
{
    const int tid = threadIdx.x;
    // B-fragment table: idx = (kit*4+nt)*64 + lane; uint4 = 4 K-dwords j=0..3
    for (int idx = tid; idx < 768; idx += 256) {
        int lane = idx & 63, kitnt = idx >> 6;
        int kit = kitnt >> 2, nt = kitnt & 3;
        int vb0 = (lane >> 4) * 4, tcol = lane & 15;
        int t = nt * 16 + tcol; int tc = (t > 48) ? 48 : t;
        uint4 o;
        unsigned* op = (unsigned*)&o;
        #pragma unroll
        for (int j = 0; j < 4; j++) {
            int v = kit * 16 + vb0 + j;
            float lo = (v <= 41) ? m_kernel[v * NCLASS + tc]        : 0.0f;
            float hi = (v <= 41) ? m_kernel[(v + KK) * NCLASS + tc] : 0.0f;
            op[j] = h2u(__halves2half2(__float2half_rn(lo), __float2half_rn(hi)));
        }
        ((uint4*)ws)[idx] = o;
    }
    // KVP paired table: one 8B-aligned uint2 per (s, n00) -> single dwordx2 load
    uint2* kvp = (uint2*)(ws + WS_KVP);
    for (int i = tid; i < NCLASS * NV; i += 256) {
        int s = i / NV, n = i - (i / NV) * NV;
        float k0 = m_kernel[n * NCLASS + s];
        float k7 = m_kernel[(n + 7) * NCLASS + s];              // n<=41 -> n+7<=48
        float k1 = m_kernel[(n + 1) * NCLASS + s];              // n+1<=42<=48
        float k8 = (n + 8 <= 48) ? m_kernel[(n + 8) * NCLASS + s] : 0.0f;
        uint2 o;
        o.x = h2u(__halves2half2(__float2half_rn(k0), __float2half_rn(k7)));
        o.y = h2u(__halves2half2(__float2half_rn(k1), __float2half_rn(k8)));
        kvp[i] = o;
    }
}

__global__ __launch_bounds__(256, 3)
void gtnet_kernel(const float* __restrict__ im_input,
                  const float* __restrict__ gt_motion,
                  float* __restrict__ out_pred,
                  float* __restrict__ out_mask,
                  const unsigned* __restrict__ ws)
{
    __shared__ __align__(16) unsigned SH[SH_TOTAL];
    unsigned* const omV   = SH + OFF_OMV;
    uint2*    const halo2 = (uint2*)(SH + OFF_HALO2);   // {pf, n8}
    float2*   const iml64 = (float2*)(SH + OFF_IML64);
    float*    const iml32 = (float*)(SH + OFF_IML32);

    const int tid  = threadIdx.x;
    const int lane = tid & 63, wv_id = tid >> 6;
    const int tx = tid & 15, ty = tid >> 4;
    const int x0 = blockIdx.x * TILE, y0 = blockIdx.y * TILE;
    const int b  = blockIdx.z;
    const int x = x0 + tx, y = y0 + ty;

    const float* mot_x = gt_motion + (size_t)b * 2 * HW;  // channel 0 -> ax
    const float* mot_y = mot_x + HW;                      // channel 1 -> ay
    const float* imP   = im_input + ((size_t)b * 6 + 3) * HW;  // last 3 channels

    // ---------------- phase 0: im halo -> REGISTERS (LDS write deferred) -------
    float2 imr01[2]; float imr2[2];
    #pragma unroll
    for (int k = 0; k < 2; k++) {
        int i = tid + k * 256;
        float2 v01 = make_float2(0.0f, 0.0f); float v2 = 0.0f;
        if (i < HH) {
            int hy = i / HALO, hx = i - hy * HALO;
            int gy = y0 - 3 + hy, gx = x0 - 3 + hx;
            if (gy >= 0 && gy < IMH && gx >= 0 && gx < IMW) {
                int off = gy * IMW + gx;
                v01.x = imP[off];
                v01.y = imP[off + HW];
                v2    = imP[off + 2 * HW];
            }
        }
        imr01[k] = v01; imr2[k] = v2;
    }

    // ---------------- phase 1: staging ----------------
    #pragma unroll
    for (int k = 0; k < 2; k++) {                       // packed motion halo
        int i = tid + k * 256;
        if (i < HH) {
            int hy = i / HALO, hx = i - hy * HALO;
            int gy = y0 - 3 + hy, gx = x0 - 3 + hx;
            unsigned pf = 0u, n8b = 0xFFFFFFFFu;        // ~0 = OOB sentinel
            if (gy >= 0 && gy < IMH && gx >= 0 && gx < IMW) {
                int off = gy * IMW + gx;
                float ay = mot_y[off] + 3.0f;
                float ax = mot_x[off] + 3.0f;
                float iyf = floorf(ay), ixf = floorf(ax);
                float fy = ay - iyf,    fx = ax - ixf;
                int n00 = (int)iyf * KK + (int)ixf;
                n00 = (n00 < 0) ? 0 : ((n00 > 40) ? 40 : n00);
                pf  = h2u(__halves2half2(__float2half_rn(fy), __float2half_rn(fx)));
                n8b = (unsigned)(n00 * 8);
            }
            uint2 hv; hv.x = pf; hv.y = n8b;
            halo2[i] = hv;                              // ds_write_b64
        }
    }
    {   // zero omV (10752 dwords) via b128
        uint4* p = reinterpret_cast<uint4*>(omV);
        for (int i = tid; i < (2 * NV * 128) / 4; i += 256) p[i] = make_uint4(0, 0, 0, 0);
    }

    // ---------------- phase 2 (HOISTED pre-barrier): m_mask dense write --------
    // Global-only (L1-hot motion reads + 49 NT stores): no LDS dependency, so
    // issuing before the barrier lets the store stream drain under phase 3.
    // Non-temporal: mask is write-once/never-read -> keep it out of L2 so the
    // shared KVP/B tables and halo reuse lines stay resident.
    {
        int off = y * IMW + x;
        float ay = mot_y[off] + 3.0f;
        float ax = mot_x[off] + 3.0f;
        float iyf = floorf(ay), ixf = floorf(ax);
        float fy = ay - iyf,    fx = ax - ixf;
        int   iy = (int)iyf,    ix = (int)ixf;
        float wyA[KK], wxB[KK];
        #pragma unroll
        for (int a = 0; a < KK; a++) {
            wyA[a] = (a == iy) ? (1.0f - fy) : ((a == iy + 1) ? fy : 0.0f);
            wxB[a] = (a == ix) ? (1.0f - fx) : ((a == ix + 1) ? fx : 0.0f);
        }
        float* mm = out_mask + (size_t)b * NCLASS * HW + off;
        #pragma unroll
        for (int a = 0; a < KK; a++)
            #pragma unroll
            for (int bb = 0; bb < KK; bb++)
                __builtin_nontemporal_store(wyA[a] * wxB[bb],
                                            mm + (size_t)(a * KK + bb) * HW);
    }

    __syncthreads();

    // ---------------- phase 3: scatter — b64 halo + VMEM KVP + om RMW ----------
    // thread-private om column (px = tid&127, half = tid>>7): no cross-thread
    // collisions; per-thread RMW ordering guaranteed by in-order DS issue.
    // KV pairs from the global KVP table (L1/L2-hot) -> off the DS pipe.
    unsigned* const omHalf = omV + (tid >> 7) * (NV * 128) + (tid & 127);
    const uint2* const kvpT = (const uint2*)(ws + WS_KVP);
    const unsigned c_m11 = 0x3C00BC00u;   // (lo=-1.0h, hi=+1.0h)
    const unsigned c_10  = 0x00003C00u;   // (lo=+1.0h, hi= 0.0h)
    #pragma unroll
    for (int u = 0; u < KK; u++) {
        uint2 hvr[KK];
        #pragma unroll
        for (int v = 0; v < KK; v++)                    // batch: 7 x ds_read_b64
            hvr[v] = halo2[(ty + u) * HALO + (tx + v)];
        unsigned n8r[KK]; uint2 kvr[KK];
        #pragma unroll
        for (int v = 0; v < KK; v++) {                  // batch: 7 x dwordx2 (L1)
            const int s = u * KK + v;                   // compile-time
            unsigned n8u = hvr[v].y;
            n8r[v] = (n8u == 0xFFFFFFFFu) ? 0u : n8u;
            kvr[v] = *(const uint2*)((const char*)(kvpT + s * NV) + n8r[v]);
        }
        #pragma unroll
        for (int v = 0; v < KK; v++) {
            unsigned pf = hvr[v].x;
            unsigned wyb, wx2;
            // wy = (1-fy, fy) : one pk_fma, fy broadcast via op_sel
            asm("v_pk_fma_f16 %0, %1, %2, %3 op_sel:[0,0,0] op_sel_hi:[0,1,1]"
                : "=v"(wyb) : "v"(pf), "v"(c_m11), "v"(c_10));
            // wx2 = (1-fx, fx) : fx broadcast via op_sel
            asm("v_pk_fma_f16 %0, %1, %2, %3 op_sel:[1,0,0] op_sel_hi:[1,1,1]"
                : "=v"(wx2) : "v"(pf), "v"(c_m11), "v"(c_10));
            wyb = (hvr[v].y == 0xFFFFFFFFu) ? 0u : wyb; // OOB -> zero weights
            unsigned tA, tB;
            // tA = wy * bcast_lo(wx2) = (w00, w10); tB = wy * bcast_hi = (w01, w11)
            asm("v_pk_mul_f16 %0, %1, %2 op_sel:[0,0] op_sel_hi:[1,0]"
                : "=v"(tA) : "v"(wyb), "v"(wx2));
            asm("v_pk_mul_f16 %0, %1, %2 op_sel:[0,1] op_sel_hi:[1,1]"
                : "=v"(tB) : "v"(wyb), "v"(wx2));
            unsigned* ob = (unsigned*)((char*)omHalf + n8r[v] * 64);  // n00*512 B
            unsigned o0 = ob[0], o1 = ob[128];          // ds_read2_b32 (0,128)
            __half2 cA = __hmul2(u2h(tA), u2h(kvr[v].x));
            __half2 cB = __hmul2(u2h(tB), u2h(kvr[v].y));
            ob[0]   = h2u(__hadd2(u2h(o0), cA));        // ds_write2_b32 (0,128)
            ob[128] = h2u(__hadd2(u2h(o1), cB));
        }
    }

    __syncthreads();   // omV complete; halo2 now dead

    // ---------------- phase 4 prologue: B fragments via 12 x b128 from ws ------
    uint4 braw[3][4];
    {
        const uint4* bsrc = (const uint4*)(ws + WS_B);
        #pragma unroll
        for (int kit = 0; kit < 3; kit++)
            #pragma unroll
            for (int nt = 0; nt < 4; nt++)
                braw[kit][nt] = bsrc[(kit * 4 + nt) * 64 + lane];
    }

    // ---------------- phase 3.5: im registers -> LDS (overlay dead region) -----
    #pragma unroll
    for (int k = 0; k < 2; k++) {
        int i = tid + k * 256;
        if (i < HH) { iml64[i] = imr01[k]; iml32[i] = imr2[k]; }
    }

    // ---------------- phase 4+5: K=96 MFMA GEMM, A = V dwords DIRECT -----------
    // W[px][t] = sum_v loV[v]*K[v][t] + hiV[v]*K[v+7][t]
    f32x4 acc[4][4];
    #pragma unroll
    for (int mt = 0; mt < 4; mt++)
        #pragma unroll
        for (int nt = 0; nt < 4; nt++)
            acc[mt][nt] = (f32x4){0.0f, 0.0f, 0.0f, 0.0f};

    const int vb0  = (lane >> 4) * 4;
    const int tcol = lane & 15;
    #pragma unroll
    for (int kit = 0; kit < 3; kit++) {
        f16x8 afk[4];
        #pragma unroll
        for (int mt = 0; mt < 4; mt++) {
            int px = wv_id * 64 + mt * 16 + tcol;
            const unsigned* pxb = omV + (px >> 7) * (NV * 128) + (px & 127);
            int vb = kit * 16 + vb0;
            union { unsigned u[4]; f16x8 v; } au;
            #pragma unroll
            for (int j = 0; j < 4; j++) {
                unsigned d = pxb[(vb + j) * 128];        // ds_read2-mergeable
                au.u[j] = (vb + j <= 41) ? d : 0u;       // mask garbage rows
            }
            afk[mt] = au.v;
        }
        #pragma unroll
        for (int mt = 0; mt < 4; mt++) {
            #pragma unroll
            for (int nt = 0; nt < 4; nt++) {
                union { uint4 q; f16x8 v; } bc; bc.q = braw[kit][nt];
                acc[mt][nt] = __builtin_amdgcn_mfma_f32_16x16x32_f16(afk[mt], bc.v, acc[mt][nt], 0, 0, 0);
            }
        }
    }

    __syncthreads();   // all omV reads done before W overwrites the region

    // ---------------- phase 5b: packed W write (16 x ds_write2_b32) ------------
    // C/D layout: col=lane&15 (t0), row=(lane>>4)*4+reg (px)
    // dword t0 of row px = (t0, t0+16); dword 16+t0 = (t0+32, t0+48)
    #pragma unroll
    for (int mt = 0; mt < 4; mt++) {
        #pragma unroll
        for (int r = 0; r < 4; r++) {
            int px = wv_id * 64 + mt * 16 + (lane >> 4) * 4 + r;
            unsigned* wrow = SH + px * WROW + tcol;
            unsigned v0 = h2u(__halves2half2(__float2half_rn(acc[mt][0][r]),
                                             __float2half_rn(acc[mt][1][r])));
            unsigned v1 = h2u(__halves2half2(__float2half_rn(acc[mt][2][r]),
                                             __float2half_rn(acc[mt][3][r])));
            wrow[0]  = v0;                               // ds_write2_b32 (0,16)
            wrow[16] = v1;
        }
    }

    __syncthreads();   // W complete; iml writes also ordered before here

    // ---------------- phase 6: apply effective 7x7 kernel ----------------------
    union { uint2 q[16]; unsigned d[32]; } wr;           // 16 x b64 (read2-merged)
    const uint2* wp = (const uint2*)(SH + tid * WROW);   // 136B stride, 8B aligned
    #pragma unroll
    for (int c = 0; c < 16; c++) wr.q[c] = wp[c];

    // static half extraction per t
    #define WHALF(t) ( (t) < 16 ? __low2half(u2h(wr.d[(t)])) :           \
                       (t) < 32 ? __high2half(u2h(wr.d[(t) - 16])) :     \
                       (t) < 48 ? __low2half(u2h(wr.d[(t) - 16])) :      \
                                  __high2half(u2h(wr.d[16])) )

    float a0 = 0.0f, a1 = 0.0f, a2 = 0.0f;
    #pragma unroll
    for (int p = 0; p < KK; p++) {
        #pragma unroll
        for (int qq = 0; qq < KK; qq++) {
            float wvv = __half2float(WHALF(p * KK + qq));
            int   hq  = (ty + p) * HALO + (tx + qq);
            float2 i01 = iml64[hq];                      // ds_read_b64
            float  i2  = iml32[hq];                      // ds_read_b32
            a0 = fmaf(wvv, i01.x, a0);
            a1 = fmaf(wvv, i01.y, a1);
            a2 = fmaf(wvv, i2,    a2);
        }
    }
    #undef WHALF
    float* pr = out_pred + (size_t)b * 3 * HW + y * IMW + x;
    __builtin_nontemporal_store(a0, pr);
    __builtin_nontemporal_store(a1, pr + HW);
    __builtin_nontemporal_store(a2, pr + 2 * HW);
}

extern "C" void kernel_launch(void* const* d_in, const int* in_sizes, int n_in,
                              void* d_out, int out_size, void* d_ws, size_t ws_size,
                              hipStream_t stream) {
    const float* im_input  = (const float*)d_in[0];
    // d_in[1] = im_output: unused by the reference computation
    const float* gt_motion = (const float*)d_in[2];
    const float* m_kernel  = (const float*)d_in[3];

    float* pred = (float*)d_out;                        // (16,3,256,256)
    float* mask = pred + (size_t)16 * 3 * HW;           // (16,49,256,256)

    hipLaunchKernelGGL(gtnet_setup, dim3(1), dim3(256), 0, stream,
                       m_kernel, (unsigned*)d_ws);

    dim3 grid(IMW / TILE, IMH / TILE, 16);
    dim3 block(256);
    hipLaunchKernelGGL(gtnet_kernel, grid, block, 0, stream,
                       im_input, gt_motion, pred, mask, (const unsigned*)d_ws);
}